// Round 5
// baseline (519.027 us; speedup 1.0000x reference)
//
#include <hip/hip_runtime.h>
#include <stdint.h>

#define B_    8
#define A_    49104
#define C_    90
#define IMG_  512.0f
#define THR_  0.2f
#define KPRE  1000
#define KOUT  100
#define NCAND 1024   // padded candidate count (power of two)
#define NKEY  2048   // compaction buffer per image
#define NBIN  1024   // histogram bins
#define BINBASE 0x17C99u   // f2ord(0.2f) >> 15
#define GANCH 64     // anchors per decode block

static __device__ __forceinline__ uint32_t f2ord(float f) {
    uint32_t b = __float_as_uint(f);
    return (b & 0x80000000u) ? ~b : (b | 0x80000000u);
}
static __device__ __forceinline__ float ord2f(uint32_t u) {
    uint32_t b = (u & 0x80000000u) ? (u & 0x7FFFFFFFu) : ~u;
    return __uint_as_float(b);
}

// ---------------------------------------------------------------- kernel 1
// LDS-coalesced per-anchor max/argmax + decode/clip + coarse histogram
__global__ __launch_bounds__(256)
void k_score_decode(const float* __restrict__ cls,
                    const float* __restrict__ loc,
                    const float* __restrict__ anc,
                    uint32_t* __restrict__ scores_u,
                    int* __restrict__ classes,
                    float* __restrict__ boxes,
                    uint32_t* __restrict__ hist) {
    __shared__ float4 s4[(GANCH * C_) / 4];          // 23040 B
    __shared__ float r_val[GANCH];
    __shared__ int   r_cls[GANCH];

    int tid = threadIdx.x;
    int b = blockIdx.y;
    int a0 = blockIdx.x * GANCH;
    int valid = A_ - a0; if (valid > GANCH) valid = GANCH;
    int n4 = (valid * C_) / 4;                       // valid is even -> exact

    const float4* src = (const float4*)(cls + (size_t)(b * A_ + a0) * C_);
    for (int i = tid; i < n4; i += 256) s4[i] = src[i];
    __syncthreads();

    const float* s = (const float*)s4;
    int g = tid >> 2, sub = tid & 3;
    float best = -1.0f; int bi = 0;
    if (g < valid) {
        #pragma unroll
        for (int j = sub; j < C_ + 2; j += 4) {      // j=sub..<90 (sub<4 => max 89)
            if (j < C_) {
                float v = s[g * C_ + j];
                if (v > best) { best = v; bi = j; }
            }
        }
    }
    // combine quad partials (first-max: larger val, then smaller idx)
    #pragma unroll
    for (int d = 1; d < 4; d <<= 1) {
        float ov = __shfl_xor(best, d);
        int   oi = __shfl_xor(bi, d);
        if (ov > best || (ov == best && oi < bi)) { best = ov; bi = oi; }
    }
    if (sub == 0 && g < valid) { r_val[g] = best; r_cls[g] = bi; }
    __syncthreads();

    // wave 0: outputs + histogram
    float m = -1.0f; int bin = 0;
    if (tid < valid) {
        int a = a0 + tid;
        int gid = b * A_ + a;
        float bv = r_val[tid];
        m = (bv > THR_) ? bv : -1.0f;
        uint32_t u = f2ord(m);
        scores_u[gid] = u;
        classes[gid]  = r_cls[tid];
        bin = (int)(u >> 15) - (int)BINBASE;
        bin = bin < 0 ? 0 : (bin >= NBIN ? NBIN - 1 : bin);

        float4 an = ((const float4*)anc)[a];
        float4 l4 = ((const float4*)loc)[gid];
        float ya = (an.x + an.z) * 0.5f;
        float xa = (an.y + an.w) * 0.5f;
        float ha = an.z - an.x;
        float wa = an.w - an.y;
        float h  = expf(l4.z) * ha;
        float w  = expf(l4.w) * wa;
        float yc = l4.x * ha + ya;
        float xc = l4.y * wa + xa;
        float4 bx;
        bx.x = fminf(fmaxf(xc - w * 0.5f, 0.0f), IMG_);
        bx.y = fminf(fmaxf(yc - h * 0.5f, 0.0f), IMG_);
        bx.z = fminf(fmaxf(xc + w * 0.5f, 0.0f), IMG_);
        bx.w = fminf(fmaxf(yc + h * 0.5f, 0.0f), IMG_);
        ((float4*)boxes)[gid] = bx;
    }

    if (tid < 64) {                                  // wave 0 only
        int lane = tid;
        bool todo = (tid < valid) && (m > THR_);
        while (__any(todo)) {
            unsigned long long actm = __ballot(todo);
            int src_l = (int)(__ffsll((long long)actm) - 1);
            int lead = __shfl(bin, src_l);
            unsigned long long same = __ballot(todo && (bin == lead));
            if (lane == src_l)
                atomicAdd(&hist[b * NBIN + lead], (uint32_t)__popcll(same));
            if (todo && bin == lead) todo = false;
        }
    }
}

// ---------------------------------------------------------------- kernel 2
// coarse cutoff: bin containing the KPRE-th value + residual rank
__global__ void k_cutoff_coarse(const uint32_t* __restrict__ hist,
                                uint32_t* __restrict__ coarse_u,
                                int* __restrict__ rem_k,
                                uint32_t* __restrict__ cutoff_u) {
    int b = blockIdx.x;
    int t = threadIdx.x;                  // 1024
    __shared__ uint32_t s[NBIN];
    s[t] = hist[b * NBIN + t];
    __syncthreads();
    for (int d = 1; d < NBIN; d <<= 1) {  // suffix scan
        uint32_t add = (t + d < NBIN) ? s[t + d] : 0u;
        __syncthreads();
        s[t] += add;
        __syncthreads();
    }
    uint32_t St = s[t];
    uint32_t Sn = (t + 1 < NBIN) ? s[t + 1] : 0u;
    if (St >= KPRE && Sn < KPRE) {
        coarse_u[b] = (BINBASE + (uint32_t)t) << 15;
        rem_k[b] = KPRE - (int)Sn;
    }
    if (t == 0 && s[0] < KPRE) {          // fewer than KPRE above threshold
        rem_k[b] = 0;
        coarse_u[b] = 0xFFFFFFFFu;        // matches nothing in fine pass
        cutoff_u[b] = BINBASE << 15;      // pass all above-threshold
    }
}

// ---------------------------------------------------------------- kernel 3
// fine histogram within the coarse bin (bits 14..5 -> 1024 bins of 32 ulps)
__global__ void k_hist_fine(const uint32_t* __restrict__ scores_u,
                            const uint32_t* __restrict__ coarse_u,
                            uint32_t* __restrict__ fhist) {
    int a = blockIdx.x * blockDim.x + threadIdx.x;
    if (a >= A_) return;
    int b = blockIdx.y;
    uint32_t u = scores_u[(size_t)b * A_ + a];
    if ((u & 0xFFFF8000u) == coarse_u[b])
        atomicAdd(&fhist[b * NBIN + ((u >> 5) & 0x3FF)], 1u);
}

// ---------------------------------------------------------------- kernel 4
// fine cutoff within the coarse bin
__global__ void k_cutoff_fine(const uint32_t* __restrict__ fhist,
                              const uint32_t* __restrict__ coarse_u,
                              const int* __restrict__ rem_k,
                              uint32_t* __restrict__ cutoff_u) {
    int b = blockIdx.x;
    int t = threadIdx.x;                  // 1024
    int rem = rem_k[b];
    __shared__ uint32_t s[NBIN];
    s[t] = fhist[b * NBIN + t];
    __syncthreads();
    for (int d = 1; d < NBIN; d <<= 1) {  // suffix scan
        uint32_t add = (t + d < NBIN) ? s[t + d] : 0u;
        __syncthreads();
        s[t] += add;
        __syncthreads();
    }
    if (rem > 0) {
        int St = (int)s[t];
        int Sn = (t + 1 < NBIN) ? (int)s[t + 1] : 0;
        if (St >= rem && Sn < rem)
            cutoff_u[b] = coarse_u[b] | ((uint32_t)t << 5);
    }
}

// ---------------------------------------------------------------- kernel 5
// compact all scores >= cutoff into 64-bit keys (score_bits << 32 | ~idx)
__global__ void k_compact(const uint32_t* __restrict__ scores_u,
                          const uint32_t* __restrict__ cutoff_u,
                          uint64_t* __restrict__ keys,
                          int* __restrict__ cnt) {
    int a = blockIdx.x * blockDim.x + threadIdx.x;
    if (a >= A_) return;
    int b = blockIdx.y;
    uint32_t u = scores_u[(size_t)b * A_ + a];
    if (u >= cutoff_u[b]) {
        int p = atomicAdd(&cnt[b], 1);
        if (p < NKEY)
            keys[(size_t)b * NKEY + p] =
                ((uint64_t)u << 32) | (uint32_t)(~(uint32_t)a);
    }
}

// ---------------------------------------------------------------- kernel 6
// exact sort by rank-counting (keys unique); emit top-NCAND candidates
__global__ void k_ranksort(const uint64_t* __restrict__ keys,
                           const int* __restrict__ cnt,
                           const int* __restrict__ classes,
                           const float* __restrict__ boxes,
                           float* __restrict__ cand_val,
                           int* __restrict__ cand_cls,
                           float* __restrict__ cand_box,
                           int* __restrict__ n_valid) {
    int b = blockIdx.x;
    int t = threadIdx.x;                  // 1024
    __shared__ uint64_t s[NKEY];
    int n = cnt[b]; if (n > NKEY) n = NKEY;
    for (int i = t; i < n; i += 1024) s[i] = keys[(size_t)b * NKEY + i];
    __syncthreads();

    uint64_t k0 = (t        < n) ? s[t]        : 0ull;
    uint64_t k1 = (t + 1024 < n) ? s[t + 1024] : 0ull;
    int r0 = 0, r1 = 0;
    #pragma unroll 4
    for (int j = 0; j < n; ++j) {
        uint64_t v = s[j];
        r0 += (v > k0);
        r1 += (v > k1);
    }
    #pragma unroll
    for (int q = 0; q < 2; ++q) {
        int i = t + q * 1024;
        int r = q == 0 ? r0 : r1;
        uint64_t k = q == 0 ? k0 : k1;
        if (i < n && r < NCAND) {
            uint32_t u = (uint32_t)(k >> 32);
            int ai = (int)(~(uint32_t)k);
            int ci = b * NCAND + r;
            cand_val[ci] = ord2f(u);
            cand_cls[ci] = classes[(size_t)b * A_ + ai];
            ((float4*)cand_box)[ci] = ((const float4*)boxes)[(size_t)b * A_ + ai];
        }
    }
    int nn = n < NCAND ? n : NCAND;
    for (int i = nn + t; i < NCAND; i += 1024) {
        int ci = b * NCAND + i;
        cand_val[ci] = -1.0f;
        cand_cls[ci] = 0;
        float4 z; z.x = z.y = z.z = z.w = 0.0f;
        ((float4*)cand_box)[ci] = z;
    }
    if (t == 0) n_valid[b] = n < KPRE ? n : KPRE;
}

// ---------------------------------------------------------------- kernel 7
// IoU > 0.2 bitmask matrix: rows [KPRE] x 64 u16 words (1024 cols)
__global__ void k_masks(const float* __restrict__ cand_box,
                        const int* __restrict__ cand_cls,
                        unsigned short* __restrict__ M16) {
    int b = blockIdx.x;
    __shared__ float x1s[NCAND], y1s[NCAND], x2s[NCAND], y2s[NCAND], ars[NCAND];
    for (int i = threadIdx.x; i < NCAND; i += blockDim.x) {
        int ci = b * NCAND + i;
        float4 bx = ((const float4*)cand_box)[ci];
        float off = (float)cand_cls[ci] * (IMG_ + 1.0f);
        float ox1 = bx.x + off, oy1 = bx.y + off;
        float ox2 = bx.z + off, oy2 = bx.w + off;
        x1s[i] = ox1; y1s[i] = oy1; x2s[i] = ox2; y2s[i] = oy2;
        ars[i] = (ox2 - ox1) * (oy2 - oy1);   // area AFTER offset, like the ref
    }
    __syncthreads();

    int row0 = blockIdx.y * 63;               // 16 chunks x 63 rows >= 1000
    for (int item = threadIdx.x; item < 63 * 64; item += blockDim.x) {
        int i = row0 + (item >> 6);
        if (i >= KPRE) continue;
        int w = item & 63;
        float xi1 = x1s[i], yi1 = y1s[i], xi2 = x2s[i], yi2 = y2s[i], ai = ars[i];
        unsigned int m = 0;
        int j0 = w * 16;
        #pragma unroll
        for (int t = 0; t < 16; ++t) {
            int j = j0 + t;
            float xx1 = fmaxf(xi1, x1s[j]);
            float yy1 = fmaxf(yi1, y1s[j]);
            float xx2 = fminf(xi2, x2s[j]);
            float yy2 = fminf(yi2, y2s[j]);
            float iw = xx2 - xx1; iw = iw > 0.0f ? iw : 0.0f;
            float ih = yy2 - yy1; ih = ih > 0.0f ? ih : 0.0f;
            float inter = iw * ih;
            float den = (ai + ars[j]) - inter + 1e-8f;   // ref associativity
            float iou = inter / den;
            m |= (iou > THR_ ? 1u : 0u) << t;
        }
        M16[((size_t)(b * NCAND + i)) * 64 + w] = (unsigned short)m;
    }
}

// ---------------------------------------------------------------- kernel 8
// sequential greedy NMS scan (1 wave/image) + output emit
__global__ void k_nms_out(const unsigned short* __restrict__ M16,
                          const float* __restrict__ cand_val,
                          const int* __restrict__ cand_cls,
                          const float* __restrict__ cand_box,
                          const int* __restrict__ n_valid,
                          float* __restrict__ out) {
    int b = blockIdx.x;
    int lane = threadIdx.x;  // 64
    int nv = n_valid[b]; if (nv > KPRE) nv = KPRE;
    const unsigned short* Mr = M16 + (size_t)b * NCAND * 64;
    __shared__ int kept[KOUT];

    uint32_t S = 0;          // 16 suppression bits per lane
    int cnt = 0;
    uint32_t cur[8], nxt[8];
    #pragma unroll
    for (int t = 0; t < 8; ++t) cur[t] = Mr[(size_t)t * 64 + lane];

    for (int base = 0; base < nv && cnt < KOUT; base += 8) {
        #pragma unroll
        for (int t = 0; t < 8; ++t) {
            int r = base + 8 + t;
            nxt[t] = Mr[(size_t)(r < NCAND ? r : 0) * 64 + lane];
        }
        #pragma unroll
        for (int t = 0; t < 8; ++t) {
            int i = base + t;
            bool inb = (i < nv) && (cnt < KOUT);
            unsigned long long ball =
                __ballot(inb && (((S >> (i & 15)) & 1u) != 0u));
            int sup = (int)((ball >> (i >> 4)) & 1ull);
            if (inb && !sup) {
                S |= cur[t];
                if (lane == 0) kept[cnt] = i;
                cnt++;
            }
        }
        #pragma unroll
        for (int t = 0; t < 8; ++t) cur[t] = nxt[t];
    }
    __syncthreads();

    for (int s_ = lane; s_ < KOUT; s_ += 64) {
        float b0 = 0.0f, b1 = 0.0f, b2 = 1.0f, b3 = 1.0f, sc = 0.0f, lb = -1.0f;
        if (s_ < cnt) {
            int i = kept[s_];
            int ci = b * NCAND + i;
            float4 bx = ((const float4*)cand_box)[ci];
            b0 = bx.x; b1 = bx.y; b2 = bx.z; b3 = bx.w;
            sc = cand_val[ci];
            lb = (float)cand_cls[ci];
        }
        int ob = (b * KOUT + s_) * 4;
        out[ob + 0] = b0; out[ob + 1] = b1; out[ob + 2] = b2; out[ob + 3] = b3;
        out[B_ * KOUT * 4 + b * KOUT + s_] = sc;          // scores
        out[B_ * KOUT * 5 + b * KOUT + s_] = lb;          // labels (as f32)
    }
}

// ----------------------------------------------------------------
extern "C" void kernel_launch(void* const* d_in, const int* in_sizes, int n_in,
                              void* d_out, int out_size, void* d_ws, size_t ws_size,
                              hipStream_t stream) {
    const float* cls = (const float*)d_in[0];
    const float* loc = (const float*)d_in[1];
    const float* anc = (const float*)d_in[2];
    float* out = (float*)d_out;

    char* ws = (char*)d_ws;
    size_t off = 0;
    auto alloc = [&](size_t bytes) -> void* {
        void* p = ws + off;
        off += (bytes + 255) & ~(size_t)255;
        return p;
    };
    uint32_t* scores_u = (uint32_t*)alloc((size_t)B_ * A_ * 4);
    int*      classes  = (int*)     alloc((size_t)B_ * A_ * 4);
    float*    boxes    = (float*)   alloc((size_t)B_ * A_ * 4 * 4);
    uint64_t* keys     = (uint64_t*)alloc((size_t)B_ * NKEY * 8);
    float*    cand_val = (float*)   alloc((size_t)B_ * NCAND * 4);
    int*      cand_cls = (int*)     alloc((size_t)B_ * NCAND * 4);
    float*    cand_box = (float*)   alloc((size_t)B_ * NCAND * 4 * 4);
    int*      n_valid  = (int*)     alloc((size_t)B_ * 4);
    unsigned short* M16 = (unsigned short*)alloc((size_t)B_ * NCAND * 64 * 2);
    // zeroed region: hist | fhist | cnt (single memset)
    char* zbase = (char*)alloc((size_t)B_ * NBIN * 4    // hist
                               + (size_t)B_ * NBIN * 4  // fhist
                               + (size_t)B_ * 4);       // cnt
    uint32_t* hist  = (uint32_t*)zbase;
    uint32_t* fhist = hist + (size_t)B_ * NBIN;
    int*      cnt   = (int*)(fhist + (size_t)B_ * NBIN);
    uint32_t* coarse_u = (uint32_t*)alloc((size_t)B_ * 4);
    int*      rem_k    = (int*)     alloc((size_t)B_ * 4);
    uint32_t* cutoff_u = (uint32_t*)alloc((size_t)B_ * 4);

    hipMemsetAsync(zbase, 0, (size_t)B_ * NBIN * 8 + (size_t)B_ * 4, stream);

    dim3 gD((A_ + GANCH - 1) / GANCH, B_);
    dim3 gA((A_ + 255) / 256, B_);
    k_score_decode<<<gD, 256, 0, stream>>>(
        cls, loc, anc, scores_u, classes, boxes, hist);
    k_cutoff_coarse<<<B_, NBIN, 0, stream>>>(hist, coarse_u, rem_k, cutoff_u);
    k_hist_fine<<<gA, 256, 0, stream>>>(scores_u, coarse_u, fhist);
    k_cutoff_fine<<<B_, NBIN, 0, stream>>>(fhist, coarse_u, rem_k, cutoff_u);
    k_compact<<<gA, 256, 0, stream>>>(scores_u, cutoff_u, keys, cnt);
    k_ranksort<<<B_, 1024, 0, stream>>>(
        keys, cnt, classes, boxes, cand_val, cand_cls, cand_box, n_valid);
    k_masks<<<dim3(B_, 16), 256, 0, stream>>>(cand_box, cand_cls, M16);
    k_nms_out<<<B_, 64, 0, stream>>>(
        M16, cand_val, cand_cls, cand_box, n_valid, out);
}

// Round 6
// 322.101 us; speedup vs baseline: 1.6114x; 1.6114x over previous
//
#include <hip/hip_runtime.h>
#include <stdint.h>

#define B_    8
#define A_    49104
#define C_    90
#define IMG_  512.0f
#define THR_  0.2f
#define KPRE  1000
#define KOUT  100
#define NCAND 1024   // padded candidate count (power of two)
#define NKEY  2048   // compaction buffer per image (LDS)
#define NBIN  1024   // histogram bins
#define BINBASE 0x17C99u     // f2ord(0.2f) >> 15
#define THRU    0xBE4CCCCDu  // f2ord(0.2f)
#define GANCH 64     // anchors per decode block

static __device__ __forceinline__ uint32_t f2ord(float f) {
    uint32_t b = __float_as_uint(f);
    return (b & 0x80000000u) ? ~b : (b | 0x80000000u);
}
static __device__ __forceinline__ float ord2f(uint32_t u) {
    uint32_t b = (u & 0x80000000u) ? (u & 0x7FFFFFFFu) : ~u;
    return __uint_as_float(b);
}

// ---------------------------------------------------------------- kernel 1
// pure streaming: LDS-coalesced max/argmax + decode/clip. NO histogram,
// NO atomics (the hist ballot loop + hot-address atomics cost ~130us in r3-r5).
__global__ __launch_bounds__(256)
void k_score_decode(const float* __restrict__ cls,
                    const float* __restrict__ loc,
                    const float* __restrict__ anc,
                    uint32_t* __restrict__ scores_u,
                    int* __restrict__ classes,
                    float* __restrict__ boxes) {
    __shared__ float4 s4[(GANCH * C_) / 4];          // 1440 float4 = 23040 B
    __shared__ float r_val[GANCH];
    __shared__ int   r_cls[GANCH];

    int tid = threadIdx.x;
    int b = blockIdx.y;
    int a0 = blockIdx.x * GANCH;
    int valid = A_ - a0; if (valid > GANCH) valid = GANCH;

    const float4* src = (const float4*)(cls + (size_t)(b * A_ + a0) * C_);
    if (valid == GANCH) {
        // full block: 1440 float4s, 6 loads issued back-to-back for MLP
        float4 v0 = src[tid];
        float4 v1 = src[tid + 256];
        float4 v2 = src[tid + 512];
        float4 v3 = src[tid + 768];
        float4 v4 = src[tid + 1024];
        float4 v5;
        if (tid < 160) v5 = src[tid + 1280];
        s4[tid]        = v0;
        s4[tid + 256]  = v1;
        s4[tid + 512]  = v2;
        s4[tid + 768]  = v3;
        s4[tid + 1024] = v4;
        if (tid < 160) s4[tid + 1280] = v5;
    } else {
        int n4 = (valid * C_) / 4;                   // valid even -> exact
        for (int i = tid; i < n4; i += 256) s4[i] = src[i];
    }
    __syncthreads();

    const float* s = (const float*)s4;
    int g = tid >> 2, sub = tid & 3;
    float best = -1.0f; int bi = 0;
    if (g < valid) {
        #pragma unroll
        for (int j = sub; j < C_ + 2; j += 4) {      // j=sub..<90
            if (j < C_) {
                float v = s[g * C_ + j];
                if (v > best) { best = v; bi = j; }
            }
        }
    }
    // combine quad partials (first-max: larger val, then smaller idx)
    #pragma unroll
    for (int d = 1; d < 4; d <<= 1) {
        float ov = __shfl_xor(best, d);
        int   oi = __shfl_xor(bi, d);
        if (ov > best || (ov == best && oi < bi)) { best = ov; bi = oi; }
    }
    if (sub == 0 && g < valid) { r_val[g] = best; r_cls[g] = bi; }
    __syncthreads();

    if (tid < valid) {                               // wave 0 lanes only
        int a = a0 + tid;
        int gid = b * A_ + a;
        float bv = r_val[tid];
        float m = (bv > THR_) ? bv : -1.0f;
        scores_u[gid] = f2ord(m);
        classes[gid]  = r_cls[tid];

        float4 an = ((const float4*)anc)[a];
        float4 l4 = ((const float4*)loc)[gid];
        float ya = (an.x + an.z) * 0.5f;
        float xa = (an.y + an.w) * 0.5f;
        float ha = an.z - an.x;
        float wa = an.w - an.y;
        float h  = expf(l4.z) * ha;
        float w  = expf(l4.w) * wa;
        float yc = l4.x * ha + ya;
        float xc = l4.y * wa + xa;
        float4 bx;
        bx.x = fminf(fmaxf(xc - w * 0.5f, 0.0f), IMG_);
        bx.y = fminf(fmaxf(yc - h * 0.5f, 0.0f), IMG_);
        bx.z = fminf(fmaxf(xc + w * 0.5f, 0.0f), IMG_);
        bx.w = fminf(fmaxf(yc + h * 0.5f, 0.0f), IMG_);
        ((float4*)boxes)[gid] = bx;
    }
}

// ---------------------------------------------------------------- kernel 2
// entire selection pipeline per image in ONE block, all state in LDS:
// coarse hist -> coarse cutoff -> fine hist -> fine cutoff -> compact -> ranksort
__global__ __launch_bounds__(1024)
void k_seltop(const uint32_t* __restrict__ scores_u,
              const int* __restrict__ classes,
              const float* __restrict__ boxes,
              float* __restrict__ cand_val,
              int* __restrict__ cand_cls,
              float* __restrict__ cand_box,
              int* __restrict__ n_valid) {
    int b = blockIdx.x;
    int t = threadIdx.x;                  // 1024
    __shared__ uint32_t h[NBIN];          // 4 KB (reused coarse->fine)
    __shared__ uint64_t keys[NKEY];       // 16 KB
    __shared__ uint32_t sh_coarse;
    __shared__ int      sh_rem;
    __shared__ uint32_t sh_cutoff;
    __shared__ int      sh_cnt;
    const uint32_t* su = scores_u + (size_t)b * A_;

    // ---- Phase A: coarse histogram (LDS atomics)
    h[t] = 0;
    if (t == 0) sh_cnt = 0;
    __syncthreads();
    for (int a = t; a < A_; a += 1024) {
        uint32_t u = su[a];
        if (u > THRU) {
            int bin = (int)(u >> 15) - (int)BINBASE;
            bin = bin < 0 ? 0 : (bin >= NBIN ? NBIN - 1 : bin);
            atomicAdd(&h[bin], 1u);
        }
    }
    __syncthreads();
    for (int d = 1; d < NBIN; d <<= 1) {  // suffix scan
        uint32_t add = (t + d < NBIN) ? h[t + d] : 0u;
        __syncthreads();
        h[t] += add;
        __syncthreads();
    }
    {
        uint32_t St = h[t];
        uint32_t Sn = (t + 1 < NBIN) ? h[t + 1] : 0u;
        if (St >= KPRE && Sn < KPRE) {
            sh_coarse = (BINBASE + (uint32_t)t) << 15;
            sh_rem = KPRE - (int)Sn;
        }
        if (t == 0 && h[0] < KPRE) {      // fewer than KPRE above threshold
            sh_rem = 0;
            sh_coarse = 0xFFFFFFFFu;      // matches nothing in fine pass
            sh_cutoff = BINBASE << 15;    // pass all above-threshold
        }
    }
    __syncthreads();
    uint32_t coarse = sh_coarse;
    int rem = sh_rem;

    // ---- Phase B: fine histogram within coarse bin (bits 14..5)
    h[t] = 0;
    __syncthreads();
    if (rem > 0) {
        for (int a = t; a < A_; a += 1024) {
            uint32_t u = su[a];
            if ((u & 0xFFFF8000u) == coarse)
                atomicAdd(&h[(u >> 5) & 0x3FF], 1u);
        }
    }
    __syncthreads();
    for (int d = 1; d < NBIN; d <<= 1) {  // suffix scan
        uint32_t add = (t + d < NBIN) ? h[t + d] : 0u;
        __syncthreads();
        h[t] += add;
        __syncthreads();
    }
    if (rem > 0) {
        int St = (int)h[t];
        int Sn = (t + 1 < NBIN) ? (int)h[t + 1] : 0;
        if (St >= rem && Sn < rem)
            sh_cutoff = coarse | ((uint32_t)t << 5);
    }
    __syncthreads();
    uint32_t cutoff = sh_cutoff;

    // ---- Phase C: compact to LDS keys
    for (int a = t; a < A_; a += 1024) {
        uint32_t u = su[a];
        if (u >= cutoff) {
            int p = atomicAdd(&sh_cnt, 1);
            if (p < NKEY)
                keys[p] = ((uint64_t)u << 32) | (uint32_t)(~(uint32_t)a);
        }
    }
    __syncthreads();
    int n = sh_cnt; if (n > NKEY) n = NKEY;

    // ---- Phase D: exact rank-sort (keys unique), emit top-NCAND
    uint64_t k0 = (t        < n) ? keys[t]        : 0ull;
    uint64_t k1 = (t + 1024 < n) ? keys[t + 1024] : 0ull;
    int r0 = 0, r1 = 0;
    #pragma unroll 4
    for (int j = 0; j < n; ++j) {
        uint64_t v = keys[j];
        r0 += (v > k0);
        r1 += (v > k1);
    }
    #pragma unroll
    for (int q = 0; q < 2; ++q) {
        int i = t + q * 1024;
        int r = q == 0 ? r0 : r1;
        uint64_t k = q == 0 ? k0 : k1;
        if (i < n && r < NCAND) {
            uint32_t u = (uint32_t)(k >> 32);
            int ai = (int)(~(uint32_t)k);
            int ci = b * NCAND + r;
            cand_val[ci] = ord2f(u);
            cand_cls[ci] = classes[(size_t)b * A_ + ai];
            ((float4*)cand_box)[ci] = ((const float4*)boxes)[(size_t)b * A_ + ai];
        }
    }
    int nn = n < NCAND ? n : NCAND;
    for (int i = nn + t; i < NCAND; i += 1024) {
        int ci = b * NCAND + i;
        cand_val[ci] = -1.0f;
        cand_cls[ci] = 0;
        float4 z; z.x = z.y = z.z = z.w = 0.0f;
        ((float4*)cand_box)[ci] = z;
    }
    if (t == 0) n_valid[b] = n < KPRE ? n : KPRE;
}

// ---------------------------------------------------------------- kernel 3
// IoU > 0.2 bitmask matrix: rows [KPRE] x 64 u16 words (1024 cols)
__global__ void k_masks(const float* __restrict__ cand_box,
                        const int* __restrict__ cand_cls,
                        unsigned short* __restrict__ M16) {
    int b = blockIdx.x;
    __shared__ float x1s[NCAND], y1s[NCAND], x2s[NCAND], y2s[NCAND], ars[NCAND];
    for (int i = threadIdx.x; i < NCAND; i += blockDim.x) {
        int ci = b * NCAND + i;
        float4 bx = ((const float4*)cand_box)[ci];
        float off = (float)cand_cls[ci] * (IMG_ + 1.0f);
        float ox1 = bx.x + off, oy1 = bx.y + off;
        float ox2 = bx.z + off, oy2 = bx.w + off;
        x1s[i] = ox1; y1s[i] = oy1; x2s[i] = ox2; y2s[i] = oy2;
        ars[i] = (ox2 - ox1) * (oy2 - oy1);   // area AFTER offset, like the ref
    }
    __syncthreads();

    int row0 = blockIdx.y * 63;               // 16 chunks x 63 rows >= 1000
    for (int item = threadIdx.x; item < 63 * 64; item += blockDim.x) {
        int i = row0 + (item >> 6);
        if (i >= KPRE) continue;
        int w = item & 63;
        float xi1 = x1s[i], yi1 = y1s[i], xi2 = x2s[i], yi2 = y2s[i], ai = ars[i];
        unsigned int m = 0;
        int j0 = w * 16;
        #pragma unroll
        for (int t = 0; t < 16; ++t) {
            int j = j0 + t;
            float xx1 = fmaxf(xi1, x1s[j]);
            float yy1 = fmaxf(yi1, y1s[j]);
            float xx2 = fminf(xi2, x2s[j]);
            float yy2 = fminf(yi2, y2s[j]);
            float iw = xx2 - xx1; iw = iw > 0.0f ? iw : 0.0f;
            float ih = yy2 - yy1; ih = ih > 0.0f ? ih : 0.0f;
            float inter = iw * ih;
            float den = (ai + ars[j]) - inter + 1e-8f;   // ref associativity
            float iou = inter / den;
            m |= (iou > THR_ ? 1u : 0u) << t;
        }
        M16[((size_t)(b * NCAND + i)) * 64 + w] = (unsigned short)m;
    }
}

// ---------------------------------------------------------------- kernel 4
// sequential greedy NMS scan (1 wave/image) + output emit
__global__ void k_nms_out(const unsigned short* __restrict__ M16,
                          const float* __restrict__ cand_val,
                          const int* __restrict__ cand_cls,
                          const float* __restrict__ cand_box,
                          const int* __restrict__ n_valid,
                          float* __restrict__ out) {
    int b = blockIdx.x;
    int lane = threadIdx.x;  // 64
    int nv = n_valid[b]; if (nv > KPRE) nv = KPRE;
    const unsigned short* Mr = M16 + (size_t)b * NCAND * 64;
    __shared__ int kept[KOUT];

    uint32_t S = 0;          // 16 suppression bits per lane
    int cnt = 0;
    uint32_t cur[8], nxt[8];
    #pragma unroll
    for (int t = 0; t < 8; ++t) cur[t] = Mr[(size_t)t * 64 + lane];

    for (int base = 0; base < nv && cnt < KOUT; base += 8) {
        #pragma unroll
        for (int t = 0; t < 8; ++t) {
            int r = base + 8 + t;
            nxt[t] = Mr[(size_t)(r < NCAND ? r : 0) * 64 + lane];
        }
        #pragma unroll
        for (int t = 0; t < 8; ++t) {
            int i = base + t;
            bool inb = (i < nv) && (cnt < KOUT);
            unsigned long long ball =
                __ballot(inb && (((S >> (i & 15)) & 1u) != 0u));
            int sup = (int)((ball >> (i >> 4)) & 1ull);
            if (inb && !sup) {
                S |= cur[t];
                if (lane == 0) kept[cnt] = i;
                cnt++;
            }
        }
        #pragma unroll
        for (int t = 0; t < 8; ++t) cur[t] = nxt[t];
    }
    __syncthreads();

    for (int s_ = lane; s_ < KOUT; s_ += 64) {
        float b0 = 0.0f, b1 = 0.0f, b2 = 1.0f, b3 = 1.0f, sc = 0.0f, lb = -1.0f;
        if (s_ < cnt) {
            int i = kept[s_];
            int ci = b * NCAND + i;
            float4 bx = ((const float4*)cand_box)[ci];
            b0 = bx.x; b1 = bx.y; b2 = bx.z; b3 = bx.w;
            sc = cand_val[ci];
            lb = (float)cand_cls[ci];
        }
        int ob = (b * KOUT + s_) * 4;
        out[ob + 0] = b0; out[ob + 1] = b1; out[ob + 2] = b2; out[ob + 3] = b3;
        out[B_ * KOUT * 4 + b * KOUT + s_] = sc;          // scores
        out[B_ * KOUT * 5 + b * KOUT + s_] = lb;          // labels (as f32)
    }
}

// ----------------------------------------------------------------
extern "C" void kernel_launch(void* const* d_in, const int* in_sizes, int n_in,
                              void* d_out, int out_size, void* d_ws, size_t ws_size,
                              hipStream_t stream) {
    const float* cls = (const float*)d_in[0];
    const float* loc = (const float*)d_in[1];
    const float* anc = (const float*)d_in[2];
    float* out = (float*)d_out;

    char* ws = (char*)d_ws;
    size_t off = 0;
    auto alloc = [&](size_t bytes) -> void* {
        void* p = ws + off;
        off += (bytes + 255) & ~(size_t)255;
        return p;
    };
    uint32_t* scores_u = (uint32_t*)alloc((size_t)B_ * A_ * 4);
    int*      classes  = (int*)     alloc((size_t)B_ * A_ * 4);
    float*    boxes    = (float*)   alloc((size_t)B_ * A_ * 4 * 4);
    float*    cand_val = (float*)   alloc((size_t)B_ * NCAND * 4);
    int*      cand_cls = (int*)     alloc((size_t)B_ * NCAND * 4);
    float*    cand_box = (float*)   alloc((size_t)B_ * NCAND * 4 * 4);
    int*      n_valid  = (int*)     alloc((size_t)B_ * 4);
    unsigned short* M16 = (unsigned short*)alloc((size_t)B_ * NCAND * 64 * 2);

    dim3 gD((A_ + GANCH - 1) / GANCH, B_);
    k_score_decode<<<gD, 256, 0, stream>>>(
        cls, loc, anc, scores_u, classes, boxes);
    k_seltop<<<B_, 1024, 0, stream>>>(
        scores_u, classes, boxes, cand_val, cand_cls, cand_box, n_valid);
    k_masks<<<dim3(B_, 16), 256, 0, stream>>>(cand_box, cand_cls, M16);
    k_nms_out<<<B_, 64, 0, stream>>>(
        M16, cand_val, cand_cls, cand_box, n_valid, out);
}

// Round 7
// 308.687 us; speedup vs baseline: 1.6814x; 1.0435x over previous
//
#include <hip/hip_runtime.h>
#include <stdint.h>

#define B_    8
#define A_    49104
#define C_    90
#define IMG_  512.0f
#define THR_  0.2f
#define KPRE  1000
#define KOUT  100
#define NCAND 1024   // padded candidate count (power of two)
#define NKEY  2048   // compaction buffer per image (LDS)
#define NBIN  1024   // histogram bins (fallback path)
#define BINBASE 0x17C99u     // f2ord(0.2f) >> 15
#define THRU    0xBE4CCCCDu  // f2ord(0.2f)
#define GANCH 64     // anchors per decode block

static __device__ __forceinline__ uint32_t f2ord(float f) {
    uint32_t b = __float_as_uint(f);
    return (b & 0x80000000u) ? ~b : (b | 0x80000000u);
}
static __device__ __forceinline__ float ord2f(uint32_t u) {
    uint32_t b = (u & 0x80000000u) ? (u & 0x7FFFFFFFu) : ~u;
    return __uint_as_float(b);
}

// ---------------------------------------------------------------- kernel 1
// pure streaming: LDS-coalesced max/argmax + decode/clip. No atomics.
__global__ __launch_bounds__(256)
void k_score_decode(const float* __restrict__ cls,
                    const float* __restrict__ loc,
                    const float* __restrict__ anc,
                    uint32_t* __restrict__ scores_u,
                    int* __restrict__ classes,
                    float* __restrict__ boxes) {
    __shared__ float4 s4[(GANCH * C_) / 4];          // 1440 float4 = 23040 B
    __shared__ float r_val[GANCH];
    __shared__ int   r_cls[GANCH];

    int tid = threadIdx.x;
    int b = blockIdx.y;
    int a0 = blockIdx.x * GANCH;
    int valid = A_ - a0; if (valid > GANCH) valid = GANCH;

    const float4* src = (const float4*)(cls + (size_t)(b * A_ + a0) * C_);
    if (valid == GANCH) {
        float4 v0 = src[tid];
        float4 v1 = src[tid + 256];
        float4 v2 = src[tid + 512];
        float4 v3 = src[tid + 768];
        float4 v4 = src[tid + 1024];
        float4 v5;
        if (tid < 160) v5 = src[tid + 1280];
        s4[tid]        = v0;
        s4[tid + 256]  = v1;
        s4[tid + 512]  = v2;
        s4[tid + 768]  = v3;
        s4[tid + 1024] = v4;
        if (tid < 160) s4[tid + 1280] = v5;
    } else {
        int n4 = (valid * C_) / 4;                   // valid even -> exact
        for (int i = tid; i < n4; i += 256) s4[i] = src[i];
    }
    __syncthreads();

    const float* s = (const float*)s4;
    int g = tid >> 2, sub = tid & 3;
    float best = -1.0f; int bi = 0;
    if (g < valid) {
        #pragma unroll
        for (int j = sub; j < C_ + 2; j += 4) {
            if (j < C_) {
                float v = s[g * C_ + j];
                if (v > best) { best = v; bi = j; }
            }
        }
    }
    #pragma unroll
    for (int d = 1; d < 4; d <<= 1) {
        float ov = __shfl_xor(best, d);
        int   oi = __shfl_xor(bi, d);
        if (ov > best || (ov == best && oi < bi)) { best = ov; bi = oi; }
    }
    if (sub == 0 && g < valid) { r_val[g] = best; r_cls[g] = bi; }
    __syncthreads();

    if (tid < valid) {
        int a = a0 + tid;
        int gid = b * A_ + a;
        float bv = r_val[tid];
        float m = (bv > THR_) ? bv : -1.0f;
        scores_u[gid] = f2ord(m);
        classes[gid]  = r_cls[tid];

        float4 an = ((const float4*)anc)[a];
        float4 l4 = ((const float4*)loc)[gid];
        float ya = (an.x + an.z) * 0.5f;
        float xa = (an.y + an.w) * 0.5f;
        float ha = an.z - an.x;
        float wa = an.w - an.y;
        float h  = expf(l4.z) * ha;
        float w  = expf(l4.w) * wa;
        float yc = l4.x * ha + ya;
        float xc = l4.y * wa + xa;
        float4 bx;
        bx.x = fminf(fmaxf(xc - w * 0.5f, 0.0f), IMG_);
        bx.y = fminf(fmaxf(yc - h * 0.5f, 0.0f), IMG_);
        bx.z = fminf(fmaxf(xc + w * 0.5f, 0.0f), IMG_);
        bx.w = fminf(fmaxf(yc + h * 0.5f, 0.0f), IMG_);
        ((float4*)boxes)[gid] = bx;
    }
}

// ---------------------------------------------------------------- kernel 2
// selection per image in ONE block. Fast path: static prefilter (score
// dist: max of 90 uniforms -> ~1308 anchors/image >= 0.9997, always
// covers the top-1000). Exact histogram fallback if the bound misses.
__global__ __launch_bounds__(1024)
void k_seltop(const uint32_t* __restrict__ scores_u,
              const int* __restrict__ classes,
              const float* __restrict__ boxes,
              float* __restrict__ cand_val,
              int* __restrict__ cand_cls,
              float* __restrict__ cand_box,
              int* __restrict__ n_valid) {
    int b = blockIdx.x;
    int t = threadIdx.x;                  // 1024
    int lane = t & 63;
    __shared__ uint64_t keys[NKEY];       // 16 KB
    __shared__ uint32_t h[NBIN];          // 4 KB (fallback only)
    __shared__ uint32_t sh_coarse;
    __shared__ int      sh_rem;
    __shared__ uint32_t sh_cutoff;
    __shared__ int      sh_cnt;
    const uint32_t* su = scores_u + (size_t)b * A_;
    const uint32_t PREF = f2ord(0.9997f);

    if (t == 0) sh_cnt = 0;
    __syncthreads();

    // ---- fast path: one vectorized pass, ballot-aggregated compaction
    const uint4* su4 = (const uint4*)su;  // A_ = 4*12276
    for (int i = t; i < A_ / 4; i += 1024) {
        uint4 v = su4[i];
        #pragma unroll
        for (int c = 0; c < 4; ++c) {
            uint32_t u = (c == 0) ? v.x : (c == 1) ? v.y : (c == 2) ? v.z : v.w;
            unsigned long long m = __ballot(u >= PREF);
            if (m) {
                uint32_t base;
                if (lane == 0) base = atomicAdd((uint32_t*)&sh_cnt, (uint32_t)__popcll(m));
                base = __shfl((int)base, 0);
                if (u >= PREF) {
                    int p = (int)base +
                            (int)__popcll(m & ((1ull << lane) - 1ull));
                    if (p < NKEY)
                        keys[p] = ((uint64_t)u << 32) |
                                  (uint32_t)(~(uint32_t)(4 * i + c));
                }
            }
        }
    }
    __syncthreads();
    int n = sh_cnt;

    if (n < KPRE || n > NKEY) {
        // ---- exact fallback: coarse hist -> fine hist -> compact
        h[t] = 0;
        if (t == 0) sh_cnt = 0;
        __syncthreads();
        for (int a = t; a < A_; a += 1024) {
            uint32_t u = su[a];
            if (u > THRU) {
                int bin = (int)(u >> 15) - (int)BINBASE;
                bin = bin < 0 ? 0 : (bin >= NBIN ? NBIN - 1 : bin);
                atomicAdd(&h[bin], 1u);
            }
        }
        __syncthreads();
        for (int d = 1; d < NBIN; d <<= 1) {
            uint32_t add = (t + d < NBIN) ? h[t + d] : 0u;
            __syncthreads();
            h[t] += add;
            __syncthreads();
        }
        {
            uint32_t St = h[t];
            uint32_t Sn = (t + 1 < NBIN) ? h[t + 1] : 0u;
            if (St >= KPRE && Sn < KPRE) {
                sh_coarse = (BINBASE + (uint32_t)t) << 15;
                sh_rem = KPRE - (int)Sn;
            }
            if (t == 0 && h[0] < KPRE) {
                sh_rem = 0;
                sh_coarse = 0xFFFFFFFFu;
                sh_cutoff = BINBASE << 15;
            }
        }
        __syncthreads();
        uint32_t coarse = sh_coarse;
        int rem = sh_rem;

        h[t] = 0;
        __syncthreads();
        if (rem > 0) {
            for (int a = t; a < A_; a += 1024) {
                uint32_t u = su[a];
                if ((u & 0xFFFF8000u) == coarse)
                    atomicAdd(&h[(u >> 5) & 0x3FF], 1u);
            }
        }
        __syncthreads();
        for (int d = 1; d < NBIN; d <<= 1) {
            uint32_t add = (t + d < NBIN) ? h[t + d] : 0u;
            __syncthreads();
            h[t] += add;
            __syncthreads();
        }
        if (rem > 0) {
            int St = (int)h[t];
            int Sn = (t + 1 < NBIN) ? (int)h[t + 1] : 0;
            if (St >= rem && Sn < rem)
                sh_cutoff = coarse | ((uint32_t)t << 5);
        }
        __syncthreads();
        uint32_t cutoff = sh_cutoff;

        for (int a = t; a < A_; a += 1024) {
            uint32_t u = su[a];
            if (u >= cutoff) {
                int p = atomicAdd(&sh_cnt, 1);
                if (p < NKEY)
                    keys[p] = ((uint64_t)u << 32) | (uint32_t)(~(uint32_t)a);
            }
        }
        __syncthreads();
        n = sh_cnt; if (n > NKEY) n = NKEY;
    }

    // ---- exact rank-sort (keys unique), emit top-NCAND
    uint64_t k0 = (t        < n) ? keys[t]        : 0ull;
    uint64_t k1 = (t + 1024 < n) ? keys[t + 1024] : 0ull;
    int r0 = 0, r1 = 0;
    #pragma unroll 4
    for (int j = 0; j < n; ++j) {
        uint64_t v = keys[j];
        r0 += (v > k0);
        r1 += (v > k1);
    }
    #pragma unroll
    for (int q = 0; q < 2; ++q) {
        int i = t + q * 1024;
        int r = q == 0 ? r0 : r1;
        uint64_t k = q == 0 ? k0 : k1;
        if (i < n && r < NCAND) {
            uint32_t u = (uint32_t)(k >> 32);
            int ai = (int)(~(uint32_t)k);
            int ci = b * NCAND + r;
            cand_val[ci] = ord2f(u);
            cand_cls[ci] = classes[(size_t)b * A_ + ai];
            ((float4*)cand_box)[ci] = ((const float4*)boxes)[(size_t)b * A_ + ai];
        }
    }
    int nn = n < NCAND ? n : NCAND;
    for (int i = nn + t; i < NCAND; i += 1024) {
        int ci = b * NCAND + i;
        cand_val[ci] = -1.0f;
        cand_cls[ci] = 0;
        float4 z; z.x = z.y = z.z = z.w = 0.0f;
        ((float4*)cand_box)[ci] = z;
    }
    if (t == 0) n_valid[b] = n < KPRE ? n : KPRE;
}

// ---------------------------------------------------------------- kernel 3
// IoU > 0.2 bitmask rows; only words w >= row>>4 are ever consulted by the
// greedy scan (column i is tested once, in increasing order, against rows
// j<i), so the lower triangle is skipped entirely.
__global__ void k_masks(const float* __restrict__ cand_box,
                        const int* __restrict__ cand_cls,
                        unsigned short* __restrict__ M16) {
    int b = blockIdx.x;
    __shared__ float x1s[NCAND], y1s[NCAND], x2s[NCAND], y2s[NCAND], ars[NCAND];
    for (int i = threadIdx.x; i < NCAND; i += blockDim.x) {
        int ci = b * NCAND + i;
        float4 bx = ((const float4*)cand_box)[ci];
        float off = (float)cand_cls[ci] * (IMG_ + 1.0f);
        float ox1 = bx.x + off, oy1 = bx.y + off;
        float ox2 = bx.z + off, oy2 = bx.w + off;
        x1s[i] = ox1; y1s[i] = oy1; x2s[i] = ox2; y2s[i] = oy2;
        ars[i] = (ox2 - ox1) * (oy2 - oy1);   // area AFTER offset, like the ref
    }
    __syncthreads();

    int row0 = blockIdx.y * 63;               // 16 chunks x 63 rows >= 1000
    for (int item = threadIdx.x; item < 63 * 64; item += blockDim.x) {
        int i = row0 + (item >> 6);
        if (i >= KPRE) continue;
        int w = item & 63;
        if (w < (i >> 4)) continue;           // dead words (cols <= i-16)
        float xi1 = x1s[i], yi1 = y1s[i], xi2 = x2s[i], yi2 = y2s[i], ai = ars[i];
        unsigned int m = 0;
        int j0 = w * 16;
        #pragma unroll
        for (int t = 0; t < 16; ++t) {
            int j = j0 + t;
            float xx1 = fmaxf(xi1, x1s[j]);
            float yy1 = fmaxf(yi1, y1s[j]);
            float xx2 = fminf(xi2, x2s[j]);
            float yy2 = fminf(yi2, y2s[j]);
            float iw = xx2 - xx1; iw = iw > 0.0f ? iw : 0.0f;
            float ih = yy2 - yy1; ih = ih > 0.0f ? ih : 0.0f;
            float inter = iw * ih;
            float den = (ai + ars[j]) - inter + 1e-8f;   // ref associativity
            float iou = inter / den;
            m |= (iou > THR_ ? 1u : 0u) << t;
        }
        M16[((size_t)(b * NCAND + i)) * 64 + w] = (unsigned short)m;
    }
}

// ---------------------------------------------------------------- kernel 4
// sequential greedy NMS scan (1 wave/image) + output emit
__global__ void k_nms_out(const unsigned short* __restrict__ M16,
                          const float* __restrict__ cand_val,
                          const int* __restrict__ cand_cls,
                          const float* __restrict__ cand_box,
                          const int* __restrict__ n_valid,
                          float* __restrict__ out) {
    int b = blockIdx.x;
    int lane = threadIdx.x;  // 64
    int nv = n_valid[b]; if (nv > KPRE) nv = KPRE;
    const unsigned short* Mr = M16 + (size_t)b * NCAND * 64;
    __shared__ int kept[KOUT];

    uint32_t S = 0;          // 16 suppression bits per lane
    int cnt = 0;
    uint32_t cur[8], nxt[8];
    #pragma unroll
    for (int t = 0; t < 8; ++t) cur[t] = Mr[(size_t)t * 64 + lane];

    for (int base = 0; base < nv && cnt < KOUT; base += 8) {
        #pragma unroll
        for (int t = 0; t < 8; ++t) {
            int r = base + 8 + t;
            nxt[t] = Mr[(size_t)(r < NCAND ? r : 0) * 64 + lane];
        }
        #pragma unroll
        for (int t = 0; t < 8; ++t) {
            int i = base + t;
            bool inb = (i < nv) && (cnt < KOUT);
            unsigned long long ball =
                __ballot(inb && (((S >> (i & 15)) & 1u) != 0u));
            int sup = (int)((ball >> (i >> 4)) & 1ull);
            if (inb && !sup) {
                S |= cur[t];
                if (lane == 0) kept[cnt] = i;
                cnt++;
            }
        }
        #pragma unroll
        for (int t = 0; t < 8; ++t) cur[t] = nxt[t];
    }
    __syncthreads();

    for (int s_ = lane; s_ < KOUT; s_ += 64) {
        float b0 = 0.0f, b1 = 0.0f, b2 = 1.0f, b3 = 1.0f, sc = 0.0f, lb = -1.0f;
        if (s_ < cnt) {
            int i = kept[s_];
            int ci = b * NCAND + i;
            float4 bx = ((const float4*)cand_box)[ci];
            b0 = bx.x; b1 = bx.y; b2 = bx.z; b3 = bx.w;
            sc = cand_val[ci];
            lb = (float)cand_cls[ci];
        }
        int ob = (b * KOUT + s_) * 4;
        out[ob + 0] = b0; out[ob + 1] = b1; out[ob + 2] = b2; out[ob + 3] = b3;
        out[B_ * KOUT * 4 + b * KOUT + s_] = sc;          // scores
        out[B_ * KOUT * 5 + b * KOUT + s_] = lb;          // labels (as f32)
    }
}

// ----------------------------------------------------------------
extern "C" void kernel_launch(void* const* d_in, const int* in_sizes, int n_in,
                              void* d_out, int out_size, void* d_ws, size_t ws_size,
                              hipStream_t stream) {
    const float* cls = (const float*)d_in[0];
    const float* loc = (const float*)d_in[1];
    const float* anc = (const float*)d_in[2];
    float* out = (float*)d_out;

    char* ws = (char*)d_ws;
    size_t off = 0;
    auto alloc = [&](size_t bytes) -> void* {
        void* p = ws + off;
        off += (bytes + 255) & ~(size_t)255;
        return p;
    };
    uint32_t* scores_u = (uint32_t*)alloc((size_t)B_ * A_ * 4);
    int*      classes  = (int*)     alloc((size_t)B_ * A_ * 4);
    float*    boxes    = (float*)   alloc((size_t)B_ * A_ * 4 * 4);
    float*    cand_val = (float*)   alloc((size_t)B_ * NCAND * 4);
    int*      cand_cls = (int*)     alloc((size_t)B_ * NCAND * 4);
    float*    cand_box = (float*)   alloc((size_t)B_ * NCAND * 4 * 4);
    int*      n_valid  = (int*)     alloc((size_t)B_ * 4);
    unsigned short* M16 = (unsigned short*)alloc((size_t)B_ * NCAND * 64 * 2);

    dim3 gD((A_ + GANCH - 1) / GANCH, B_);
    k_score_decode<<<gD, 256, 0, stream>>>(
        cls, loc, anc, scores_u, classes, boxes);
    k_seltop<<<B_, 1024, 0, stream>>>(
        scores_u, classes, boxes, cand_val, cand_cls, cand_box, n_valid);
    k_masks<<<dim3(B_, 16), 256, 0, stream>>>(cand_box, cand_cls, M16);
    k_nms_out<<<B_, 64, 0, stream>>>(
        M16, cand_val, cand_cls, cand_box, n_valid, out);
}